// Round 1
// baseline (254.502 us; speedup 1.0000x reference)
//
#include <hip/hip_runtime.h>
#include <stdint.h>

// MaskedMHSA: B=2 T=2048 E=768 H=12 DH=64
// x:[B,T,E] f32; Wq/Wk/Wv:[H,E,DH]; bq/bk/bv:[H,DH]; Wo:[E,E]; bo:[E]; gamma,beta:[E]
// out = x + LN(concat_heads(causal_attn(xWq, xWk, xWv)) @ Wo + bo)

#define NROWS 4096      // B*T
#define EMB   768
#define NQKV  2304      // 3*E
#define TSEQ  2048
#define NHEAD 12
#define NBH   24        // B*H

typedef unsigned short u16;
typedef u16  ushort8 __attribute__((ext_vector_type(8)));
typedef __bf16 bf16x8 __attribute__((ext_vector_type(8)));
typedef float f32x4 __attribute__((ext_vector_type(4)));

typedef const __attribute__((address_space(1))) void* gas_ptr;
typedef __attribute__((address_space(3))) void* las_ptr;

__device__ __forceinline__ u16 f2bf(float f) {
  union { float f; uint32_t u; } v; v.f = f;
  uint32_t u = v.u;
  return (u16)((u + 0x7fffu + ((u >> 16) & 1u)) >> 16);
}

// ---------------- pack kernels ----------------
__global__ __launch_bounds__(256) void k_pack_x(const float* __restrict__ x, u16* __restrict__ xb) {
  int i = (blockIdx.x * 256 + threadIdx.x) * 8;
  float4 a = *(const float4*)(x + i);
  float4 b = *(const float4*)(x + i + 4);
  ushort8 o;
  o[0]=f2bf(a.x); o[1]=f2bf(a.y); o[2]=f2bf(a.z); o[3]=f2bf(a.w);
  o[4]=f2bf(b.x); o[5]=f2bf(b.y); o[6]=f2bf(b.z); o[7]=f2bf(b.w);
  *(ushort8*)(xb + i) = o;
}

// wt[n][e] = W{q,k,v}[h][e][d]  (n = sel*768 + h*64 + d), bias[n] likewise
__global__ __launch_bounds__(256) void k_pack_wqkv(const float* __restrict__ Wq, const float* __restrict__ Wk,
                            const float* __restrict__ Wv, const float* __restrict__ bq,
                            const float* __restrict__ bk, const float* __restrict__ bv,
                            u16* __restrict__ wt, float* __restrict__ bias) {
  int idx = blockIdx.x * 256 + threadIdx.x;
  if (idx >= NQKV * EMB) return;
  int n = idx / EMB, e = idx - n * EMB;
  int sel = n / EMB;
  int c = n - sel * EMB;
  int h = c >> 6, d = c & 63;
  const float* W = sel == 0 ? Wq : (sel == 1 ? Wk : Wv);
  wt[idx] = f2bf(W[((size_t)h * EMB + e) * 64 + d]);
  if (e == 0) {
    const float* bs = sel == 0 ? bq : (sel == 1 ? bk : bv);
    bias[n] = bs[h * 64 + d];
  }
}

// wot[n][e] = Wo[e][n]
__global__ __launch_bounds__(256) void k_pack_wo(const float* __restrict__ Wo, u16* __restrict__ wot) {
  int idx = blockIdx.x * 256 + threadIdx.x;
  if (idx >= EMB * EMB) return;
  int n = idx / EMB, e = idx - n * EMB;
  wot[idx] = f2bf(Wo[(size_t)e * EMB + n]);
}

// ---------------- GEMM: C[M,N] = A[M,K] * Bt[N,K]^T + bias ----------------
// 128x128 tile, BK=32, 4 waves (2x2), m97-style global_load_lds staging.
template<int OUT_F32>
__global__ __launch_bounds__(256) void k_gemm(const u16* __restrict__ A, const u16* __restrict__ Bt,
                                              const float* __restrict__ bias, void* __restrict__ Cout,
                                              int M, int N, int K) {
  __shared__ u16 lds_a[128 * 32];
  __shared__ u16 lds_b[128 * 32];
  int tid = threadIdx.x;
  int w = tid >> 6, lane = tid & 63;
  int wr = w >> 1, wc = w & 1;
  int m0 = blockIdx.x * 128, n0 = blockIdx.y * 128;
  int lrow = lane & 15, lk8 = (lane >> 4) * 8;

  f32x4 zero = {0.f, 0.f, 0.f, 0.f};
  f32x4 acc[4][4];
  for (int m = 0; m < 4; ++m) for (int n = 0; n < 4; ++n) acc[m][n] = zero;

  int sr = tid >> 2;          // staging row within 64-row chunk pattern
  int sk = (tid & 3) * 8;     // staging k offset

  for (int k0 = 0; k0 < K; k0 += 32) {
#pragma unroll
    for (int c = 0; c < 2; ++c) {
      int r = c * 64 + sr;
      const u16* ga = A  + (size_t)(m0 + r) * K + k0 + sk;
      const u16* gb = Bt + (size_t)(n0 + r) * K + k0 + sk;
      u16* la = lds_a + c * 2048 + w * 512;   // wave-uniform LDS base (bytes: c*4096 + w*1024)
      u16* lb = lds_b + c * 2048 + w * 512;
      __builtin_amdgcn_global_load_lds((gas_ptr)ga, (las_ptr)la, 16, 0, 0);
      __builtin_amdgcn_global_load_lds((gas_ptr)gb, (las_ptr)lb, 16, 0, 0);
    }
    __syncthreads();
    bf16x8 af[4], bfr[4];
#pragma unroll
    for (int m = 0; m < 4; ++m)
      af[m] = *(const bf16x8*)(lds_a + (wr * 64 + m * 16 + lrow) * 32 + lk8);
#pragma unroll
    for (int n = 0; n < 4; ++n)
      bfr[n] = *(const bf16x8*)(lds_b + (wc * 64 + n * 16 + lrow) * 32 + lk8);
#pragma unroll
    for (int m = 0; m < 4; ++m)
#pragma unroll
      for (int n = 0; n < 4; ++n)
        acc[m][n] = __builtin_amdgcn_mfma_f32_16x16x32_bf16(af[m], bfr[n], acc[m][n], 0, 0, 0);
    __syncthreads();
  }

#pragma unroll
  for (int m = 0; m < 4; ++m)
#pragma unroll
    for (int n = 0; n < 4; ++n) {
      int col = n0 + wc * 64 + n * 16 + lrow;
      float bcol = bias[col];
#pragma unroll
      for (int r = 0; r < 4; ++r) {
        int row = m0 + wr * 64 + m * 16 + (lane >> 4) * 4 + r;
        float v = acc[m][n][r] + bcol;
        if (OUT_F32) ((float*)Cout)[(size_t)row * N + col] = v;
        else         ((u16*)Cout)[(size_t)row * N + col] = f2bf(v);
      }
    }
}

// ---------------- V transpose: vt[bh][d][t] from qkv[t][1536 + h*64 + d] ----------------
__global__ __launch_bounds__(256) void k_transpose_v(const u16* __restrict__ qkv, u16* __restrict__ vt) {
  __shared__ u16 lds[64][65];
  int bh = blockIdx.y;
  int b = bh / NHEAD, h = bh - b * NHEAD;
  int t0 = blockIdx.x * 64;
  int tid = threadIdx.x;
  int r = tid >> 2, c0 = (tid & 3) * 16;
  const u16* src = qkv + (size_t)(b * TSEQ + t0 + r) * NQKV + 2 * EMB + h * 64 + c0;
  ushort8 v0 = *(const ushort8*)(src);
  ushort8 v1 = *(const ushort8*)(src + 8);
#pragma unroll
  for (int j = 0; j < 8; ++j) { lds[r][c0 + j] = v0[j]; lds[r][c0 + 8 + j] = v1[j]; }
  __syncthreads();
  int d = tid >> 2, tt = (tid & 3) * 16;
  ushort8 o0, o1;
#pragma unroll
  for (int j = 0; j < 8; ++j) { o0[j] = lds[tt + j][d]; o1[j] = lds[tt + 8 + j][d]; }
  u16* dst = vt + (size_t)(bh * 64 + d) * TSEQ + t0 + tt;
  *(ushort8*)dst = o0;
  *(ushort8*)(dst + 8) = o1;
}

// ---------------- causal flash attention ----------------
// grid (32, 24); 4 independent waves/block, each owns 16 q-rows; K-tiles of 32.
__global__ __launch_bounds__(256) void k_attn(const u16* __restrict__ qkv, const u16* __restrict__ vt,
                                              u16* __restrict__ aout) {
  __shared__ u16 ldsp[4][16 * 32];
  int tid = threadIdx.x;
  int w = tid >> 6, lane = tid & 63;
  int bh = blockIdx.y;
  int b = bh / NHEAD, h = bh - b * NHEAD;
  int qrow0 = blockIdx.x * 64 + w * 16;
  int lrow = lane & 15, lg = lane >> 4;

  const u16* qp = qkv + (size_t)(b * TSEQ + qrow0 + lrow) * NQKV + h * 64;
  bf16x8 aq0 = *(const bf16x8*)(qp + lg * 8);
  bf16x8 aq1 = *(const bf16x8*)(qp + 32 + lg * 8);

  f32x4 zero = {0.f, 0.f, 0.f, 0.f};
  f32x4 o[4]; for (int n = 0; n < 4; ++n) o[n] = zero;
  float mr[4], lr[4];
#pragma unroll
  for (int r = 0; r < 4; ++r) { mr[r] = -3e30f; lr[r] = 0.f; }

  const float sc = 0.125f * 1.44269504f;  // 1/sqrt(64) * log2(e)
  int ktmax = (qrow0 + 15) >> 5;
  u16* pb = &ldsp[w][0];
  const u16* kbase = qkv + EMB + h * 64;
  const u16* vbase = vt + (size_t)bh * 64 * TSEQ;

  for (int kt = 0; kt <= ktmax; ++kt) {
    int s0 = kt * 32;
    f32x4 s0a = zero, s1a = zero;
    {
      const u16* kp0 = kbase + (size_t)(b * TSEQ + s0 + lrow) * NQKV;
      const u16* kp1 = kbase + (size_t)(b * TSEQ + s0 + 16 + lrow) * NQKV;
      bf16x8 k00 = *(const bf16x8*)(kp0 + lg * 8);
      bf16x8 k01 = *(const bf16x8*)(kp0 + 32 + lg * 8);
      bf16x8 k10 = *(const bf16x8*)(kp1 + lg * 8);
      bf16x8 k11 = *(const bf16x8*)(kp1 + 32 + lg * 8);
      s0a = __builtin_amdgcn_mfma_f32_16x16x32_bf16(aq0, k00, s0a, 0, 0, 0);
      s0a = __builtin_amdgcn_mfma_f32_16x16x32_bf16(aq1, k01, s0a, 0, 0, 0);
      s1a = __builtin_amdgcn_mfma_f32_16x16x32_bf16(aq0, k10, s1a, 0, 0, 0);
      s1a = __builtin_amdgcn_mfma_f32_16x16x32_bf16(aq1, k11, s1a, 0, 0, 0);
    }
    bool needmask = (s0 + 31) > qrow0;
    float p0[4], p1[4], tm[4];
#pragma unroll
    for (int r = 0; r < 4; ++r) {
      int q = qrow0 + lg * 4 + r;
      float v0 = s0a[r] * sc, v1 = s1a[r] * sc;
      if (needmask) {
        if (s0 + lrow > q)      v0 = -3e30f;
        if (s0 + 16 + lrow > q) v1 = -3e30f;
      }
      p0[r] = v0; p1[r] = v1;
      tm[r] = fmaxf(v0, v1);
    }
#pragma unroll
    for (int r = 0; r < 4; ++r) {
      float t = tm[r];
      t = fmaxf(t, __shfl_xor(t, 1));
      t = fmaxf(t, __shfl_xor(t, 2));
      t = fmaxf(t, __shfl_xor(t, 4));
      t = fmaxf(t, __shfl_xor(t, 8));
      float nm = fmaxf(mr[r], t);
      float alpha = __builtin_amdgcn_exp2f(mr[r] - nm);
      mr[r] = nm;
      float e0 = __builtin_amdgcn_exp2f(p0[r] - nm);
      float e1 = __builtin_amdgcn_exp2f(p1[r] - nm);
      p0[r] = e0; p1[r] = e1;
      float rs = e0 + e1;
      rs += __shfl_xor(rs, 1);
      rs += __shfl_xor(rs, 2);
      rs += __shfl_xor(rs, 4);
      rs += __shfl_xor(rs, 8);
      lr[r] = lr[r] * alpha + rs;
#pragma unroll
      for (int n = 0; n < 4; ++n) o[n][r] *= alpha;
    }
    // P -> LDS (per-wave buffer), then read back as MFMA A-fragment
#pragma unroll
    for (int r = 0; r < 4; ++r) {
      pb[(lg * 4 + r) * 32 + lrow]      = f2bf(p0[r]);
      pb[(lg * 4 + r) * 32 + 16 + lrow] = f2bf(p1[r]);
    }
    asm volatile("s_waitcnt lgkmcnt(0)" ::: "memory");
    bf16x8 ap = *(const bf16x8*)(pb + lrow * 32 + lg * 8);
#pragma unroll
    for (int n = 0; n < 4; ++n) {
      bf16x8 bv = *(const bf16x8*)(vbase + (size_t)(n * 16 + lrow) * TSEQ + s0 + lg * 8);
      o[n] = __builtin_amdgcn_mfma_f32_16x16x32_bf16(ap, bv, o[n], 0, 0, 0);
    }
  }
#pragma unroll
  for (int n = 0; n < 4; ++n)
#pragma unroll
    for (int r = 0; r < 4; ++r) {
      int q = qrow0 + lg * 4 + r;
      float v = o[n][r] / lr[r];
      aout[(size_t)(b * TSEQ + q) * EMB + h * 64 + n * 16 + lrow] = f2bf(v);
    }
}

// ---------------- LayerNorm + residual ----------------
__global__ __launch_bounds__(256) void k_ln_res(const float* __restrict__ proj, const float* __restrict__ x,
                                                const float* __restrict__ gamma, const float* __restrict__ beta,
                                                float* __restrict__ out) {
  __shared__ float smem[2][4];
  int row = blockIdx.x;
  const float* pr = proj + (size_t)row * EMB;
  const float* xr = x + (size_t)row * EMB;
  float* orow = out + (size_t)row * EMB;
  int tid = threadIdx.x;
  float v[3];
  float s = 0.f, s2 = 0.f;
#pragma unroll
  for (int i = 0; i < 3; ++i) { v[i] = pr[tid + 256 * i]; s += v[i]; s2 += v[i] * v[i]; }
#pragma unroll
  for (int m = 1; m < 64; m <<= 1) { s += __shfl_xor(s, m); s2 += __shfl_xor(s2, m); }
  int w = tid >> 6, lane = tid & 63;
  if (lane == 0) { smem[0][w] = s; smem[1][w] = s2; }
  __syncthreads();
  s  = smem[0][0] + smem[0][1] + smem[0][2] + smem[0][3];
  s2 = smem[1][0] + smem[1][1] + smem[1][2] + smem[1][3];
  float mu = s * (1.f / EMB);
  float var = s2 * (1.f / EMB) - mu * mu;
  float rstd = rsqrtf(var + 1e-5f);
#pragma unroll
  for (int i = 0; i < 3; ++i) {
    int c = tid + 256 * i;
    orow[c] = xr[c] + (v[i] - mu) * rstd * gamma[c] + beta[c];
  }
}

// ---------------- launch ----------------
extern "C" void kernel_launch(void* const* d_in, const int* in_sizes, int n_in,
                              void* d_out, int out_size, void* d_ws, size_t ws_size,
                              hipStream_t stream) {
  const float* x     = (const float*)d_in[0];
  const float* Wq    = (const float*)d_in[1];
  const float* bq    = (const float*)d_in[2];
  const float* Wk    = (const float*)d_in[3];
  const float* bk    = (const float*)d_in[4];
  const float* Wv    = (const float*)d_in[5];
  const float* bv    = (const float*)d_in[6];
  const float* Wo    = (const float*)d_in[7];
  const float* bo    = (const float*)d_in[8];
  const float* gamma = (const float*)d_in[9];
  const float* beta  = (const float*)d_in[10];
  float* out = (float*)d_out;

  char* ws = (char*)d_ws;
  size_t off = 0;
  u16* xb    = (u16*)(ws + off); off += (size_t)NROWS * EMB * 2;     // 6.29 MB
  u16* wqkvt = (u16*)(ws + off); off += (size_t)NQKV * EMB * 2;      // 3.54 MB
  u16* wot   = (u16*)(ws + off); off += (size_t)EMB * EMB * 2;       // 1.18 MB
  float* bqkv = (float*)(ws + off); off += (size_t)NQKV * 4;         // 9 KB
  u16* qkv   = (u16*)(ws + off); off += (size_t)NROWS * NQKV * 2;    // 18.9 MB
  u16* vt    = (u16*)(ws + off); off += (size_t)NBH * 64 * TSEQ * 2; // 6.29 MB
  u16* aout  = (u16*)(ws + off); off += (size_t)NROWS * EMB * 2;     // 6.29 MB
  float* proj = (float*)qkv;  // alias: qkv dead after attention

  k_pack_x<<<NROWS * EMB / (256 * 8), 256, 0, stream>>>(x, xb);
  k_pack_wqkv<<<(NQKV * EMB + 255) / 256, 256, 0, stream>>>(Wq, Wk, Wv, bq, bk, bv, wqkvt, bqkv);
  k_pack_wo<<<(EMB * EMB + 255) / 256, 256, 0, stream>>>(Wo, wot);
  k_gemm<0><<<dim3(NROWS / 128, NQKV / 128), 256, 0, stream>>>(xb, wqkvt, bqkv, qkv, NROWS, NQKV, EMB);
  k_transpose_v<<<dim3(TSEQ / 64, NBH), 256, 0, stream>>>(qkv, vt);
  k_attn<<<dim3(TSEQ / 64, NBH), 256, 0, stream>>>(qkv, vt, aout);
  k_gemm<1><<<dim3(NROWS / 128, EMB / 128), 256, 0, stream>>>(aout, wot, bo, proj, NROWS, EMB, EMB);
  k_ln_res<<<NROWS, 256, 0, stream>>>(proj, x, gamma, beta, out);
}

// Round 2
// 133.479 us; speedup vs baseline: 1.9067x; 1.9067x over previous
//
#include <hip/hip_runtime.h>
#include <stdint.h>

// MaskedMHSA: B=2 T=2048 E=768 H=12 DH=64
#define NROWS 4096      // B*T
#define EMB   768
#define NQKV  2304      // 3*E
#define TSEQ  2048
#define NHEAD 12
#define NBH   24        // B*H

typedef unsigned short u16;
typedef u16  ushort8 __attribute__((ext_vector_type(8)));
typedef __bf16 bf16x8 __attribute__((ext_vector_type(8)));
typedef float f32x4 __attribute__((ext_vector_type(4)));

typedef const __attribute__((address_space(1))) void* gas_ptr;
typedef __attribute__((address_space(3))) void* las_ptr;

__device__ __forceinline__ u16 f2bf(float f) {
  union { float f; uint32_t u; } v; v.f = f;
  uint32_t u = v.u;
  return (u16)((u + 0x7fffu + ((u >> 16) & 1u)) >> 16);
}
__device__ __forceinline__ uint32_t pk2(float a, float b) {
  return (uint32_t)f2bf(a) | ((uint32_t)f2bf(b) << 16);
}

#define VMCNT4 asm volatile("s_waitcnt vmcnt(4)" ::: "memory")
#define VMCNT0 asm volatile("s_waitcnt vmcnt(0)" ::: "memory")
#define LGKM0  asm volatile("s_waitcnt lgkmcnt(0)" ::: "memory")
#define SBAR   __builtin_amdgcn_s_barrier()
#define SCHED0 __builtin_amdgcn_sched_barrier(0)

// ---------------- pack kernels ----------------
__global__ __launch_bounds__(256) void k_pack_x(const float* __restrict__ x, u16* __restrict__ xb) {
  int i = (blockIdx.x * 256 + threadIdx.x) * 8;
  float4 a = *(const float4*)(x + i);
  float4 b = *(const float4*)(x + i + 4);
  ushort8 o;
  o[0]=f2bf(a.x); o[1]=f2bf(a.y); o[2]=f2bf(a.z); o[3]=f2bf(a.w);
  o[4]=f2bf(b.x); o[5]=f2bf(b.y); o[6]=f2bf(b.z); o[7]=f2bf(b.w);
  *(ushort8*)(xb + i) = o;
}

__global__ __launch_bounds__(256) void k_pack_wqkv(const float* __restrict__ Wq, const float* __restrict__ Wk,
                            const float* __restrict__ Wv, const float* __restrict__ bq,
                            const float* __restrict__ bk, const float* __restrict__ bv,
                            u16* __restrict__ wt, float* __restrict__ bias) {
  int idx = blockIdx.x * 256 + threadIdx.x;
  if (idx >= NQKV * EMB) return;
  int n = idx / EMB, e = idx - n * EMB;
  int sel = n / EMB;
  int c = n - sel * EMB;
  int h = c >> 6, d = c & 63;
  const float* W = sel == 0 ? Wq : (sel == 1 ? Wk : Wv);
  wt[idx] = f2bf(W[((size_t)h * EMB + e) * 64 + d]);
  if (e == 0) {
    const float* bs = sel == 0 ? bq : (sel == 1 ? bk : bv);
    bias[n] = bs[h * 64 + d];
  }
}

__global__ __launch_bounds__(256) void k_pack_wo(const float* __restrict__ Wo, u16* __restrict__ wot) {
  int idx = blockIdx.x * 256 + threadIdx.x;
  if (idx >= EMB * EMB) return;
  int n = idx / EMB, e = idx - n * EMB;
  wot[idx] = f2bf(Wo[(size_t)e * EMB + n]);
}

// ---------------- GEMM: C[M,N] = A[M,K] * Bt[N,K]^T + bias ----------------
template<int OUT_F32>
__global__ __launch_bounds__(256) void k_gemm(const u16* __restrict__ A, const u16* __restrict__ Bt,
                                              const float* __restrict__ bias, void* __restrict__ Cout,
                                              int M, int N, int K) {
  __shared__ u16 lds_a[128 * 32];
  __shared__ u16 lds_b[128 * 32];
  int tid = threadIdx.x;
  int w = tid >> 6, lane = tid & 63;
  int wr = w >> 1, wc = w & 1;
  int m0 = blockIdx.x * 128, n0 = blockIdx.y * 128;
  int lrow = lane & 15, lk8 = (lane >> 4) * 8;

  f32x4 zero = {0.f, 0.f, 0.f, 0.f};
  f32x4 acc[4][4];
  for (int m = 0; m < 4; ++m) for (int n = 0; n < 4; ++n) acc[m][n] = zero;

  int sr = tid >> 2;
  int sk = (tid & 3) * 8;

  for (int k0 = 0; k0 < K; k0 += 32) {
#pragma unroll
    for (int c = 0; c < 2; ++c) {
      int r = c * 64 + sr;
      const u16* ga = A  + (size_t)(m0 + r) * K + k0 + sk;
      const u16* gb = Bt + (size_t)(n0 + r) * K + k0 + sk;
      u16* la = lds_a + c * 2048 + w * 512;
      u16* lb = lds_b + c * 2048 + w * 512;
      __builtin_amdgcn_global_load_lds((gas_ptr)ga, (las_ptr)la, 16, 0, 0);
      __builtin_amdgcn_global_load_lds((gas_ptr)gb, (las_ptr)lb, 16, 0, 0);
    }
    __syncthreads();
    bf16x8 af[4], bfr[4];
#pragma unroll
    for (int m = 0; m < 4; ++m)
      af[m] = *(const bf16x8*)(lds_a + (wr * 64 + m * 16 + lrow) * 32 + lk8);
#pragma unroll
    for (int n = 0; n < 4; ++n)
      bfr[n] = *(const bf16x8*)(lds_b + (wc * 64 + n * 16 + lrow) * 32 + lk8);
#pragma unroll
    for (int m = 0; m < 4; ++m)
#pragma unroll
      for (int n = 0; n < 4; ++n)
        acc[m][n] = __builtin_amdgcn_mfma_f32_16x16x32_bf16(af[m], bfr[n], acc[m][n], 0, 0, 0);
    __syncthreads();
  }

#pragma unroll
  for (int m = 0; m < 4; ++m)
#pragma unroll
    for (int n = 0; n < 4; ++n) {
      int col = n0 + wc * 64 + n * 16 + lrow;
      float bcol = bias[col];
#pragma unroll
      for (int r = 0; r < 4; ++r) {
        int row = m0 + wr * 64 + m * 16 + (lane >> 4) * 4 + r;
        float v = acc[m][n][r] + bcol;
        if (OUT_F32) ((float*)Cout)[(size_t)row * N + col] = v;
        else         ((u16*)Cout)[(size_t)row * N + col] = f2bf(v);
      }
    }
}

// ---------------- V transpose: vt[bh][d][t] ----------------
__global__ __launch_bounds__(256) void k_transpose_v(const u16* __restrict__ qkv, u16* __restrict__ vt) {
  __shared__ u16 lds[64][65];
  int bh = blockIdx.y;
  int b = bh / NHEAD, h = bh - b * NHEAD;
  int t0 = blockIdx.x * 64;
  int tid = threadIdx.x;
  int r = tid >> 2, c0 = (tid & 3) * 16;
  const u16* src = qkv + (size_t)(b * TSEQ + t0 + r) * NQKV + 2 * EMB + h * 64 + c0;
  ushort8 v0 = *(const ushort8*)(src);
  ushort8 v1 = *(const ushort8*)(src + 8);
#pragma unroll
  for (int j = 0; j < 8; ++j) { lds[r][c0 + j] = v0[j]; lds[r][c0 + 8 + j] = v1[j]; }
  __syncthreads();
  int d = tid >> 2, tt = (tid & 3) * 16;
  ushort8 o0, o1;
#pragma unroll
  for (int j = 0; j < 8; ++j) { o0[j] = lds[tt + j][d]; o1[j] = lds[tt + 8 + j][d]; }
  u16* dst = vt + (size_t)(bh * 64 + d) * TSEQ + t0 + tt;
  *(ushort8*)dst = o0;
  *(ushort8*)(dst + 8) = o1;
}

// ---------------- causal flash attention (rewritten) ----------------
// grid (32, 24), 256 thr. Block handles 64 q-rows of one (b,h); wave w owns
// rows qblk*64 + w*16 .. +15. Swapped QK^T (lane&15 = q), K/V staged in LDS
// (double-buffered, XOR-swizzled via pre-swizzled global src), KVBLK=64.
__global__ __launch_bounds__(256) void k_attn(const u16* __restrict__ qkv, const u16* __restrict__ vt,
                                              u16* __restrict__ aout) {
  __shared__ u16 kbuf[2][64 * 64];
  __shared__ u16 vbuf[2][64 * 64];
  __shared__ u16 pbuf[4][16 * 64];
  int tid = threadIdx.x;
  int w = tid >> 6, lane = tid & 63;
  int ql = lane & 15, g = lane >> 4;
  int y = blockIdx.y;
  int b = y / NHEAD, h = y - b * NHEAD;
  int x = blockIdx.x;
  // balanced causal permutation: co-resident blocks (ids +256 apart share x)
  // get q-tiles {x, (x+16)&31, x<16?30-2x:63-2x} -> tile-count sum 49/50.
  int kk = y >> 3;
  int qblk = (kk == 0) ? x : (kk == 1) ? ((x + 16) & 31) : (x < 16 ? 30 - 2 * x : 63 - 2 * x);
  int nt = qblk + 1;
  int qrow0w = qblk * 64 + w * 16;
  int qg = qrow0w + ql;               // this lane's q row (for softmax stats)

  // Q fragments (B-operand: col=lane&15=q, k=8g+j)
  const u16* qp = qkv + (size_t)(b * TSEQ + qg) * NQKV + h * 64;
  bf16x8 bq0 = *(const bf16x8*)(qp + g * 8);
  bf16x8 bq1 = *(const bf16x8*)(qp + 32 + g * 8);

  // staging
  const u16* kst = qkv + (size_t)(b * TSEQ) * NQKV + EMB + h * 64;
  const u16* vst = vt + (size_t)y * 64 * TSEQ;
  int srow = tid >> 3, scol = tid & 7;

  f32x4 zero = {0.f, 0.f, 0.f, 0.f};
  f32x4 o[4]; for (int n = 0; n < 4; ++n) o[n] = zero;
  float m_run = -1e30f, l_run = 0.f;
  const float sc2 = 0.18033688f;  // (1/8) * log2(e)
  u16* pw = &pbuf[w][0];
  int swz = (ql & 7) << 3;        // element-granular XOR (16B)

  auto STAGE = [&](int bi, int kt_) {
#pragma unroll
    for (int i = 0; i < 2; ++i) {
      int row = i * 32 + srow;
      int c16 = scol ^ (row & 7);
      const u16* gk = kst + (size_t)(kt_ * 64 + row) * NQKV + c16 * 8;
      __builtin_amdgcn_global_load_lds((gas_ptr)gk, (las_ptr)(&kbuf[bi][i * 2048 + w * 512]), 16, 0, 0);
      const u16* gv = vst + (size_t)row * TSEQ + kt_ * 64 + c16 * 8;
      __builtin_amdgcn_global_load_lds((gas_ptr)gv, (las_ptr)(&vbuf[bi][i * 2048 + w * 512]), 16, 0, 0);
    }
  };

  STAGE(0, 0);
  for (int kt = 0; kt < nt; ++kt) {
    int cur = kt & 1;
    if (kt + 1 < nt) { STAGE(cur ^ 1, kt + 1); VMCNT4; } else { VMCNT0; }
    SBAR;

    const u16* kb = &kbuf[cur][0];
    const u16* vb = &vbuf[cur][0];
    int s0 = kt * 64;

    // QK^T swapped: st[sblk] lane holds S^T[s = s0+sblk*16+4g+r][q = qg]
    f32x4 st[4];
#pragma unroll
    for (int sblk = 0; sblk < 4; ++sblk) {
      int row = sblk * 16 + ql;
      bf16x8 ka0 = *(const bf16x8*)(kb + ((row * 64 + 8 * g) ^ swz));
      bf16x8 ka1 = *(const bf16x8*)(kb + ((row * 64 + 32 + 8 * g) ^ swz));
      f32x4 acc = zero;
      acc = __builtin_amdgcn_mfma_f32_16x16x32_bf16(ka0, bq0, acc, 0, 0, 0);
      acc = __builtin_amdgcn_mfma_f32_16x16x32_bf16(ka1, bq1, acc, 0, 0, 0);
      st[sblk] = acc;
    }

    // scale + causal mask (only last tile can violate causality)
    float v[4][4];
    bool lastt = (kt == nt - 1);
#pragma unroll
    for (int sblk = 0; sblk < 4; ++sblk)
#pragma unroll
      for (int r = 0; r < 4; ++r) {
        float vv = st[sblk][r] * sc2;
        if (lastt) {
          int sg = s0 + sblk * 16 + 4 * g + r;
          if (sg > qg) vv = -1e30f;
        }
        v[sblk][r] = vv;
      }

    // softmax (per-lane row, then reduce over g via 2 shfls)
    float tmax = v[0][0];
#pragma unroll
    for (int sblk = 0; sblk < 4; ++sblk)
#pragma unroll
      for (int r = 0; r < 4; ++r) tmax = fmaxf(tmax, v[sblk][r]);
    tmax = fmaxf(tmax, __shfl_xor(tmax, 16));
    tmax = fmaxf(tmax, __shfl_xor(tmax, 32));
    float nm = fmaxf(m_run, tmax);
    float alpha = __builtin_amdgcn_exp2f(m_run - nm);
    m_run = nm;
    float rs = 0.f;
#pragma unroll
    for (int sblk = 0; sblk < 4; ++sblk)
#pragma unroll
      for (int r = 0; r < 4; ++r) {
        float e = __builtin_amdgcn_exp2f(v[sblk][r] - nm);
        v[sblk][r] = e;
        rs += e;
      }
    rs += __shfl_xor(rs, 16);
    rs += __shfl_xor(rs, 32);
    l_run = l_run * alpha + rs;

    // broadcast alpha to O-layout rows (q = 4g+r) and rescale O
    float al[4];
#pragma unroll
    for (int r = 0; r < 4; ++r) al[r] = __shfl(alpha, 4 * g + r);
#pragma unroll
    for (int n = 0; n < 4; ++n)
#pragma unroll
      for (int r = 0; r < 4; ++r) o[n][r] *= al[r];

    // P^T -> per-wave LDS [q][s] (swizzled), read back as PV A-fragments
#pragma unroll
    for (int sblk = 0; sblk < 4; ++sblk) {
      uint2 dw;
      dw.x = pk2(v[sblk][0], v[sblk][1]);
      dw.y = pk2(v[sblk][2], v[sblk][3]);
      *(uint2*)(pw + ((ql * 64 + sblk * 16 + 4 * g) ^ swz)) = dw;
    }
    LGKM0; SCHED0;
    bf16x8 ap0 = *(const bf16x8*)(pw + ((ql * 64 + 8 * g) ^ swz));
    bf16x8 ap1 = *(const bf16x8*)(pw + ((ql * 64 + 32 + 8 * g) ^ swz));

    // PV: O[q][d] += P[q][s] * Vt[d][s]
#pragma unroll
    for (int n = 0; n < 4; ++n) {
      int row = n * 16 + ql;
      bf16x8 vb0 = *(const bf16x8*)(vb + ((row * 64 + 8 * g) ^ swz));
      bf16x8 vb1 = *(const bf16x8*)(vb + ((row * 64 + 32 + 8 * g) ^ swz));
      o[n] = __builtin_amdgcn_mfma_f32_16x16x32_bf16(ap0, vb0, o[n], 0, 0, 0);
      o[n] = __builtin_amdgcn_mfma_f32_16x16x32_bf16(ap1, vb1, o[n], 0, 0, 0);
    }
    SBAR;
  }

  float linv = 1.0f / l_run;
  float li[4];
#pragma unroll
  for (int r = 0; r < 4; ++r) li[r] = __shfl(linv, 4 * g + r);
#pragma unroll
  for (int n = 0; n < 4; ++n)
#pragma unroll
    for (int r = 0; r < 4; ++r) {
      int q = qrow0w + 4 * g + r;
      aout[(size_t)(b * TSEQ + q) * EMB + h * 64 + n * 16 + ql] = f2bf(o[n][r] * li[r]);
    }
}

// ---------------- LayerNorm + residual ----------------
__global__ __launch_bounds__(256) void k_ln_res(const float* __restrict__ proj, const float* __restrict__ x,
                                                const float* __restrict__ gamma, const float* __restrict__ beta,
                                                float* __restrict__ out) {
  __shared__ float smem[2][4];
  int row = blockIdx.x;
  const float* pr = proj + (size_t)row * EMB;
  const float* xr = x + (size_t)row * EMB;
  float* orow = out + (size_t)row * EMB;
  int tid = threadIdx.x;
  float v[3];
  float s = 0.f, s2 = 0.f;
#pragma unroll
  for (int i = 0; i < 3; ++i) { v[i] = pr[tid + 256 * i]; s += v[i]; s2 += v[i] * v[i]; }
#pragma unroll
  for (int m = 1; m < 64; m <<= 1) { s += __shfl_xor(s, m); s2 += __shfl_xor(s2, m); }
  int w = tid >> 6, lane = tid & 63;
  if (lane == 0) { smem[0][w] = s; smem[1][w] = s2; }
  __syncthreads();
  s  = smem[0][0] + smem[0][1] + smem[0][2] + smem[0][3];
  s2 = smem[1][0] + smem[1][1] + smem[1][2] + smem[1][3];
  float mu = s * (1.f / EMB);
  float var = s2 * (1.f / EMB) - mu * mu;
  float rstd = rsqrtf(var + 1e-5f);
#pragma unroll
  for (int i = 0; i < 3; ++i) {
    int c = tid + 256 * i;
    orow[c] = xr[c] + (v[i] - mu) * rstd * gamma[c] + beta[c];
  }
}

// ---------------- launch ----------------
extern "C" void kernel_launch(void* const* d_in, const int* in_sizes, int n_in,
                              void* d_out, int out_size, void* d_ws, size_t ws_size,
                              hipStream_t stream) {
  const float* x     = (const float*)d_in[0];
  const float* Wq    = (const float*)d_in[1];
  const float* bq    = (const float*)d_in[2];
  const float* Wk    = (const float*)d_in[3];
  const float* bk    = (const float*)d_in[4];
  const float* Wv    = (const float*)d_in[5];
  const float* bv    = (const float*)d_in[6];
  const float* Wo    = (const float*)d_in[7];
  const float* bo    = (const float*)d_in[8];
  const float* gamma = (const float*)d_in[9];
  const float* beta  = (const float*)d_in[10];
  float* out = (float*)d_out;

  char* ws = (char*)d_ws;
  size_t off = 0;
  u16* xb    = (u16*)(ws + off); off += (size_t)NROWS * EMB * 2;
  u16* wqkvt = (u16*)(ws + off); off += (size_t)NQKV * EMB * 2;
  u16* wot   = (u16*)(ws + off); off += (size_t)EMB * EMB * 2;
  float* bqkv = (float*)(ws + off); off += (size_t)NQKV * 4;
  u16* qkv   = (u16*)(ws + off); off += (size_t)NROWS * NQKV * 2;
  u16* vt    = (u16*)(ws + off); off += (size_t)NBH * 64 * TSEQ * 2;
  u16* aout  = (u16*)(ws + off); off += (size_t)NROWS * EMB * 2;
  float* proj = (float*)qkv;  // alias: qkv dead after attention

  k_pack_x<<<NROWS * EMB / (256 * 8), 256, 0, stream>>>(x, xb);
  k_pack_wqkv<<<(NQKV * EMB + 255) / 256, 256, 0, stream>>>(Wq, Wk, Wv, bq, bk, bv, wqkvt, bqkv);
  k_pack_wo<<<(EMB * EMB + 255) / 256, 256, 0, stream>>>(Wo, wot);
  k_gemm<0><<<dim3(NROWS / 128, NQKV / 128), 256, 0, stream>>>(xb, wqkvt, bqkv, qkv, NROWS, NQKV, EMB);
  k_transpose_v<<<dim3(TSEQ / 64, NBH), 256, 0, stream>>>(qkv, vt);
  k_attn<<<dim3(32, NBH), 256, 0, stream>>>(qkv, vt, aout);
  k_gemm<1><<<dim3(NROWS / 128, EMB / 128), 256, 0, stream>>>(aout, wot, bo, proj, NROWS, EMB, EMB);
  k_ln_res<<<NROWS, 256, 0, stream>>>(proj, x, gamma, beta, out);
}